// Round 6
// baseline (352.853 us; speedup 1.0000x reference)
//
#include <hip/hip_runtime.h>
#include <stdint.h>

#define T_TOK 2048
#define DD 1024
#define EE 8
#define FF 2048
#define NSLOT 4096     // T*K
#define SLOTPAD 4224   // NSLOT + 128 pad rows

typedef __attribute__((ext_vector_type(8))) __bf16 bf16x8;
typedef __attribute__((ext_vector_type(4))) float floatx4;
typedef __attribute__((ext_vector_type(8))) unsigned short ushort8;

__device__ __forceinline__ unsigned short f2bf(float f){
  union { float f; unsigned u; } v; v.f = f;
  unsigned r = v.u + 0x7fffu + ((v.u >> 16) & 1u);
  return (unsigned short)(r >> 16);
}
__device__ __forceinline__ float bf2f(unsigned short h){
  union { unsigned u; float f; } v; v.u = (unsigned)h << 16; return v.f;
}

// ---------------- RMSNorm + router (one block per token, NO global atomics) ----
__global__ __launch_bounds__(256) void k_rms_router(
    const float* __restrict__ x, const float* __restrict__ gw,
    const float* __restrict__ nw,
    unsigned short* __restrict__ xn,
    int* __restrict__ topk_id, float* __restrict__ topk_w,
    float* __restrict__ probbuf)
{
  const int t = blockIdx.x, tid = threadIdx.x;
  const float4 xv = ((const float4*)(x + (size_t)t * DD))[tid];
  float ss = xv.x*xv.x + xv.y*xv.y + xv.z*xv.z + xv.w*xv.w;
  #pragma unroll
  for (int o = 32; o > 0; o >>= 1) ss += __shfl_down(ss, o);
  __shared__ float s_ss[4];
  __shared__ float s_p[4][8];
  if ((tid & 63) == 0) s_ss[tid >> 6] = ss;
  __syncthreads();
  const float tot = s_ss[0] + s_ss[1] + s_ss[2] + s_ss[3];
  const float inv = rsqrtf(tot * (1.0f / DD) + 1.1920929e-7f);
  const float4 nv = ((const float4*)nw)[tid];
  float4 xnv;
  xnv.x = xv.x*inv*nv.x; xnv.y = xv.y*inv*nv.y;
  xnv.z = xv.z*inv*nv.z; xnv.w = xv.w*inv*nv.w;
  ushort4 bv; bv.x = f2bf(xnv.x); bv.y = f2bf(xnv.y); bv.z = f2bf(xnv.z); bv.w = f2bf(xnv.w);
  ((ushort4*)(xn + (size_t)t * DD))[tid] = bv;
  float p[8];
  #pragma unroll
  for (int e = 0; e < 8; e++){
    const float4 g = ((const float4*)(gw + e * DD))[tid];
    p[e] = xnv.x*g.x + xnv.y*g.y + xnv.z*g.z + xnv.w*g.w;
  }
  #pragma unroll
  for (int e = 0; e < 8; e++){
    #pragma unroll
    for (int o = 32; o > 0; o >>= 1) p[e] += __shfl_down(p[e], o);
  }
  if ((tid & 63) == 0){
    #pragma unroll
    for (int e = 0; e < 8; e++) s_p[tid >> 6][e] = p[e];
  }
  __syncthreads();
  if (tid == 0){
    float lg[8], pr[8];
    #pragma unroll
    for (int e = 0; e < 8; e++) lg[e] = s_p[0][e] + s_p[1][e] + s_p[2][e] + s_p[3][e];
    float mx = lg[0];
    for (int e = 1; e < 8; e++) mx = fmaxf(mx, lg[e]);
    float sum = 0.f;
    for (int e = 0; e < 8; e++){ pr[e] = __expf(lg[e] - mx); sum += pr[e]; }
    const float is = 1.f / sum;
    for (int e = 0; e < 8; e++) pr[e] *= is;
    #pragma unroll
    for (int e = 0; e < 8; e++) probbuf[t * 8 + e] = pr[e];
    int e1 = 0;
    for (int e = 1; e < 8; e++) if (pr[e] > pr[e1]) e1 = e;       // first max (tie: lower idx)
    int e2 = (e1 == 0) ? 1 : 0;
    for (int e = 0; e < 8; e++) if (e != e1 && e != e2 && pr[e] > pr[e2]) e2 = e;
    const float wsum = fmaxf(pr[e1] + pr[e2], 1e-6f);
    topk_id[2*t] = e1; topk_id[2*t+1] = e2;
    topk_w[2*t] = pr[e1] / wsum; topk_w[2*t+1] = pr[e2] / wsum;
  }
}

// ------- single-block: counts, bases, lb loss, deterministic slot assignment ----
__global__ __launch_bounds__(256) void k_stats(
    const int* __restrict__ topk_id, const float* __restrict__ topk_w,
    const float* __restrict__ probbuf,
    int* __restrict__ counts, int* __restrict__ bases,
    int* __restrict__ slots_of, int* __restrict__ tok_of,
    float* __restrict__ slot_w,
    float* __restrict__ lb_out)
{
  const int tid = threadIdx.x;
  __shared__ int s_scan[256][8];
  __shared__ int s_base[8];

  int ids[16];
  int lc[8] = {}, lc1[8] = {};
  float lsp[8] = {};
  #pragma unroll
  for (int j = 0; j < 8; j++){
    const int t = tid * 8 + j;
    const int e1 = topk_id[2*t], e2 = topk_id[2*t+1];
    ids[2*j] = e1; ids[2*j+1] = e2;
    lc[e1]++; lc[e2]++; lc1[e1]++;
    const float4 p0 = ((const float4*)(probbuf + t * 8))[0];
    const float4 p1 = ((const float4*)(probbuf + t * 8))[1];
    lsp[0] += p0.x; lsp[1] += p0.y; lsp[2] += p0.z; lsp[3] += p0.w;
    lsp[4] += p1.x; lsp[5] += p1.y; lsp[6] += p1.z; lsp[7] += p1.w;
  }
  #pragma unroll
  for (int e = 0; e < 8; e++) s_scan[tid][e] = lc[e];
  __syncthreads();
  for (int off = 1; off < 256; off <<= 1){
    int v[8];
    if (tid >= off){
      #pragma unroll
      for (int e = 0; e < 8; e++) v[e] = s_scan[tid - off][e];
    }
    __syncthreads();
    if (tid >= off){
      #pragma unroll
      for (int e = 0; e < 8; e++) s_scan[tid][e] += v[e];
    }
    __syncthreads();
  }
  int   rc1[8]; float rsp[8];
  #pragma unroll
  for (int e = 0; e < 8; e++){ rc1[e] = lc1[e]; rsp[e] = lsp[e]; }
  #pragma unroll
  for (int e = 0; e < 8; e++){
    #pragma unroll
    for (int o = 32; o > 0; o >>= 1){
      rc1[e] += __shfl_down(rc1[e], o);
      rsp[e] += __shfl_down(rsp[e], o);
    }
  }
  __shared__ int   s_c1[4][8];
  __shared__ float s_sp[4][8];
  if ((tid & 63) == 0){
    const int w = tid >> 6;
    #pragma unroll
    for (int e = 0; e < 8; e++){ s_c1[w][e] = rc1[e]; s_sp[w][e] = rsp[e]; }
  }
  __syncthreads();
  if (tid == 0){
    int b = 0; float lb = 0.f;
    for (int e = 0; e < 8; e++){
      const int tot = s_scan[255][e];
      counts[e] = tot; bases[e] = b; s_base[e] = b; b += tot;
      const int   c1 = s_c1[0][e] + s_c1[1][e] + s_c1[2][e] + s_c1[3][e];
      const float sp = s_sp[0][e] + s_sp[1][e] + s_sp[2][e] + s_sp[3][e];
      lb += (float)c1 * sp;
    }
    lb_out[0] = 8.f * lb * (1.f / ((float)T_TOK * (float)T_TOK));
  }
  __syncthreads();
  int rank[8];
  #pragma unroll
  for (int e = 0; e < 8; e++) rank[e] = s_scan[tid][e] - lc[e];   // exclusive prefix
  #pragma unroll
  for (int j = 0; j < 8; j++){
    const int t = tid * 8 + j;
    #pragma unroll
    for (int k = 0; k < 2; k++){
      const int e = ids[2*j + k];
      const int slot = s_base[e] + rank[e]++;
      slots_of[2*t + k] = slot;
      tok_of[slot] = t;
      slot_w[slot] = topk_w[2*t + k];
    }
  }
}

// -------- grouped GEMM: bf16 A (async LDS) x fp32 B (same-iter load+cvt+ds_write) ----
// Weights cross HBM once (no convert pass). expert = blockIdx&7 (XCD-local).
// mt varies fastest -> co-resident blocks on an XCD share one B nt-tile (~0.5MB)
// + the whole A (~1MB) in its 4MB L2. LDS chunk swizzle pos=(q+(row>>1))&3 keeps
// fragment ds_read_b128 conflict-free. All pad-row sources clamped to valid rows
// (no reads of unwritten workspace -> output is a pure function of d_in).
// MODE 0 (+indirect A): C = silu(xn[tok_of[slot]] @ B^T) -> bf16 Hg
// MODE 1 (direct A):    C = (A @ B^T) * slot_w[row] -> bf16 Og
template<int KDIM, int NDIM, int MODE>
__global__ __launch_bounds__(256) void k_gemm(
    const unsigned short* __restrict__ Ag,
    const float* __restrict__ Bw,
    const int* __restrict__ counts, const int* __restrict__ bases,
    const int* __restrict__ tok_of,
    const float* __restrict__ slot_w,
    unsigned short* __restrict__ Cout)
{
  constexpr int NT = NDIM / 128;
  const int e  = blockIdx.x & 7;
  const int g  = blockIdx.x >> 3;
  const int nt = g / 16;            // mt fastest
  const int mt = g - nt * 16;
  const int M = counts[e];
  if (mt * 128 >= M) return;
  const int sbase = bases[e];

  __shared__ __align__(16) unsigned short As[128 * 32];
  __shared__ __align__(16) unsigned short Bs[128 * 32];

  const int tid = threadIdx.x;
  const int l = tid & 63;
  const int w = tid >> 6;
  const int wm = (w >> 1) * 64, wn = (w & 1) * 64;
  const int lrow = l & 15, lq = l >> 4;          // k-quad 0..3 (8 elems each)

  // per-thread staging geometry: chunks c = tid, tid+256 ; c = row*4 + q
  const unsigned short* arow[2];
  const float* brow[2];
  int kcs[2];
  #pragma unroll
  for (int i = 0; i < 2; i++){
    const int c = tid + i * 256;
    const int row = c >> 2, q = c & 3;
    kcs[i] = ((q - (row >> 1)) & 3) * 8;         // swizzled source k-chunk (elements)
    const int vrow = min(mt * 128 + row, M - 1); // clamp pad rows to valid (M>=1 here)
    if (MODE == 0){
      arow[i] = Ag + (size_t)tok_of[sbase + vrow] * KDIM;
    } else {
      arow[i] = Ag + (size_t)(sbase + vrow) * KDIM;
    }
    brow[i] = Bw + (size_t)e * NDIM * KDIM + (size_t)(nt * 128 + row) * KDIM + kcs[i];
  }

  floatx4 acc[4][4] = {};

  for (int k0 = 0; k0 < KDIM; k0 += 32){
    // A: async bf16 global->LDS
    #pragma unroll
    for (int i = 0; i < 2; i++){
      const int c = tid + i * 256;
      __builtin_amdgcn_global_load_lds(
          (__attribute__((address_space(1))) unsigned int*)(arow[i] + k0 + kcs[i]),
          (__attribute__((address_space(3))) unsigned int*)(As + c * 8), 16, 0, 0);
    }
    // B: load fp32 -> cvt -> LDS (pure RAW chain, no cross-iteration registers)
    #pragma unroll
    for (int i = 0; i < 2; i++){
      const float4* p = (const float4*)(brow[i] + k0);
      const float4 b0 = p[0], b1 = p[1];
      ushort8 o;
      o[0] = f2bf(b0.x); o[1] = f2bf(b0.y); o[2] = f2bf(b0.z); o[3] = f2bf(b0.w);
      o[4] = f2bf(b1.x); o[5] = f2bf(b1.y); o[6] = f2bf(b1.z); o[7] = f2bf(b1.w);
      *(ushort8*)(Bs + (size_t)(tid + i * 256) * 8) = o;
    }
    __syncthreads();
    bf16x8 af[4], bfv[4];
    #pragma unroll
    for (int mi = 0; mi < 4; mi++){
      const int row = wm + mi * 16 + lrow;
      const int p = (lq + (row >> 1)) & 3;
      af[mi] = *(const bf16x8*)(As + row * 32 + p * 8);
    }
    #pragma unroll
    for (int ni = 0; ni < 4; ni++){
      const int row = wn + ni * 16 + lrow;
      const int p = (lq + (row >> 1)) & 3;
      bfv[ni] = *(const bf16x8*)(Bs + row * 32 + p * 8);
    }
    #pragma unroll
    for (int mi = 0; mi < 4; mi++)
      #pragma unroll
      for (int ni = 0; ni < 4; ni++)
        acc[mi][ni] = __builtin_amdgcn_mfma_f32_16x16x32_bf16(af[mi], bfv[ni], acc[mi][ni], 0, 0, 0);
    __syncthreads();
  }

  // epilogue: C/D layout col = lane&15, row = (lane>>4)*4 + r
  const int rb = lq * 4;
  #pragma unroll
  for (int mi = 0; mi < 4; mi++){
    #pragma unroll
    for (int r = 0; r < 4; r++){
      const int row = mt * 128 + wm + mi * 16 + rb + r;
      if (row < M){
        #pragma unroll
        for (int ni = 0; ni < 4; ni++){
          const int col = nt * 128 + wn + ni * 16 + (l & 15);
          const float v = acc[mi][ni][r];
          if (MODE == 0){
            const float s = v / (1.f + __expf(-v));   // silu
            Cout[(size_t)(sbase + row) * NDIM + col] = f2bf(s);
          } else {
            const float wgt = slot_w[sbase + row];
            Cout[(size_t)(sbase + row) * NDIM + col] = f2bf(v * wgt);
          }
        }
      }
    }
  }
}

// ---------------- residual combine (Og is bf16) ----------------
__global__ __launch_bounds__(256) void k_combine(
    const float* __restrict__ x, const unsigned short* __restrict__ Og,
    const int* __restrict__ slots_of, const float* __restrict__ scale,
    float* __restrict__ out)
{
  const int i = blockIdx.x * 256 + threadIdx.x;   // over T*D/8
  const int t = i >> 7;
  const int j = i & 127;
  const int s0 = slots_of[2*t], s1 = slots_of[2*t+1];
  const ushort8 a = ((const ushort8*)(Og + (size_t)s0 * DD))[j];
  const ushort8 b = ((const ushort8*)(Og + (size_t)s1 * DD))[j];
  const float4 x0 = ((const float4*)(x + (size_t)t * DD))[2*j];
  const float4 x1 = ((const float4*)(x + (size_t)t * DD))[2*j + 1];
  const float sc = 1.f / (1.f + __expf(-scale[0]));
  float4 o0, o1;
  o0.x = x0.x + sc * (bf2f(a[0]) + bf2f(b[0]));
  o0.y = x0.y + sc * (bf2f(a[1]) + bf2f(b[1]));
  o0.z = x0.z + sc * (bf2f(a[2]) + bf2f(b[2]));
  o0.w = x0.w + sc * (bf2f(a[3]) + bf2f(b[3]));
  o1.x = x1.x + sc * (bf2f(a[4]) + bf2f(b[4]));
  o1.y = x1.y + sc * (bf2f(a[5]) + bf2f(b[5]));
  o1.z = x1.z + sc * (bf2f(a[6]) + bf2f(b[6]));
  o1.w = x1.w + sc * (bf2f(a[7]) + bf2f(b[7]));
  ((float4*)(out + (size_t)t * DD))[2*j] = o0;
  ((float4*)(out + (size_t)t * DD))[2*j + 1] = o1;
}

extern "C" void kernel_launch(void* const* d_in, const int* in_sizes, int n_in,
                              void* d_out, int out_size, void* d_ws, size_t ws_size,
                              hipStream_t stream)
{
  const float* x     = (const float*)d_in[0];   // [2,1024,1024]
  const float* gw    = (const float*)d_in[1];   // [8,1024]
  const float* w1    = (const float*)d_in[2];   // [8,2048,1024]
  const float* w2    = (const float*)d_in[3];   // [8,1024,2048]
  const float* nw    = (const float*)d_in[4];   // [1024]
  const float* scale = (const float*)d_in[5];   // [1]
  float* out = (float*)d_out;                   // 2097152 + 1 (lb loss)

  char* ws = (char*)d_ws;
  int*   counts  = (int*)(ws + 0);
  int*   bases   = (int*)(ws + 64);
  int*   topk_id = (int*)(ws + 1024);            // 16 KB
  float* topk_w  = (float*)(ws + 20480);         // 16 KB
  int*   slots_of= (int*)(ws + 40960);           // 16 KB
  float* slot_w  = (float*)(ws + 61440);         // 16.5 KB
  int*   tok_of  = (int*)(ws + 81920);           // 16 KB
  float* probbuf = (float*)(ws + 102400);        // 64 KB
  unsigned short* xn  = (unsigned short*)(ws + 262144);
  unsigned short* Hg  = xn + (size_t)T_TOK * DD;
  unsigned short* Og  = Hg + (size_t)SLOTPAD * FF;

  k_rms_router<<<T_TOK, 256, 0, stream>>>(x, gw, nw, xn, topk_id, topk_w, probbuf);
  k_stats<<<1, 256, 0, stream>>>(topk_id, topk_w, probbuf, counts, bases,
                                 slots_of, tok_of, slot_w, out + (size_t)T_TOK * DD);
  k_gemm<1024, 2048, 0><<<EE * 16 * (FF/128), 256, 0, stream>>>(xn, w1, counts, bases, tok_of, nullptr, Hg);
  k_gemm<2048, 1024, 1><<<EE * 16 * (DD/128), 256, 0, stream>>>(Hg, w2, counts, bases, nullptr, slot_w, Og);
  k_combine<<<T_TOK * DD / 8 / 256, 256, 0, stream>>>(x, Og, slots_of, scale, out);
}

// Round 7
// 292.872 us; speedup vs baseline: 1.2048x; 1.2048x over previous
//
#include <hip/hip_runtime.h>
#include <stdint.h>

#define T_TOK 2048
#define DD 1024
#define EE 8
#define FF 2048
#define NSLOT 4096     // T*K
#define SLOTPAD 4224   // NSLOT + 128 pad rows

typedef __attribute__((ext_vector_type(8))) __bf16 bf16x8;
typedef __attribute__((ext_vector_type(4))) float floatx4;
typedef __attribute__((ext_vector_type(8))) unsigned short ushort8;

__device__ __forceinline__ unsigned short f2bf(float f){
  union { float f; unsigned u; } v; v.f = f;
  unsigned r = v.u + 0x7fffu + ((v.u >> 16) & 1u);
  return (unsigned short)(r >> 16);
}
__device__ __forceinline__ float bf2f(unsigned short h){
  union { unsigned u; float f; } v; v.u = (unsigned)h << 16; return v.f;
}

#define GLDS(src, dst) __builtin_amdgcn_global_load_lds( \
    (__attribute__((address_space(1))) unsigned int*)(src), \
    (__attribute__((address_space(3))) unsigned int*)(dst), 16, 0, 0)

// ---------------- RMSNorm + router (one block per token, NO global atomics) ----
__global__ __launch_bounds__(256) void k_rms_router(
    const float* __restrict__ x, const float* __restrict__ gw,
    const float* __restrict__ nw,
    unsigned short* __restrict__ xn,
    int* __restrict__ topk_id, float* __restrict__ topk_w,
    float* __restrict__ probbuf)
{
  const int t = blockIdx.x, tid = threadIdx.x;
  const float4 xv = ((const float4*)(x + (size_t)t * DD))[tid];
  float ss = xv.x*xv.x + xv.y*xv.y + xv.z*xv.z + xv.w*xv.w;
  #pragma unroll
  for (int o = 32; o > 0; o >>= 1) ss += __shfl_down(ss, o);
  __shared__ float s_ss[4];
  __shared__ float s_p[4][8];
  if ((tid & 63) == 0) s_ss[tid >> 6] = ss;
  __syncthreads();
  const float tot = s_ss[0] + s_ss[1] + s_ss[2] + s_ss[3];
  const float inv = rsqrtf(tot * (1.0f / DD) + 1.1920929e-7f);
  const float4 nv = ((const float4*)nw)[tid];
  float4 xnv;
  xnv.x = xv.x*inv*nv.x; xnv.y = xv.y*inv*nv.y;
  xnv.z = xv.z*inv*nv.z; xnv.w = xv.w*inv*nv.w;
  ushort4 bv; bv.x = f2bf(xnv.x); bv.y = f2bf(xnv.y); bv.z = f2bf(xnv.z); bv.w = f2bf(xnv.w);
  ((ushort4*)(xn + (size_t)t * DD))[tid] = bv;
  float p[8];
  #pragma unroll
  for (int e = 0; e < 8; e++){
    const float4 g = ((const float4*)(gw + e * DD))[tid];
    p[e] = xnv.x*g.x + xnv.y*g.y + xnv.z*g.z + xnv.w*g.w;
  }
  #pragma unroll
  for (int e = 0; e < 8; e++){
    #pragma unroll
    for (int o = 32; o > 0; o >>= 1) p[e] += __shfl_down(p[e], o);
  }
  if ((tid & 63) == 0){
    #pragma unroll
    for (int e = 0; e < 8; e++) s_p[tid >> 6][e] = p[e];
  }
  __syncthreads();
  if (tid == 0){
    float lg[8], pr[8];
    #pragma unroll
    for (int e = 0; e < 8; e++) lg[e] = s_p[0][e] + s_p[1][e] + s_p[2][e] + s_p[3][e];
    float mx = lg[0];
    for (int e = 1; e < 8; e++) mx = fmaxf(mx, lg[e]);
    float sum = 0.f;
    for (int e = 0; e < 8; e++){ pr[e] = __expf(lg[e] - mx); sum += pr[e]; }
    const float is = 1.f / sum;
    for (int e = 0; e < 8; e++) pr[e] *= is;
    #pragma unroll
    for (int e = 0; e < 8; e++) probbuf[t * 8 + e] = pr[e];
    int e1 = 0;
    for (int e = 1; e < 8; e++) if (pr[e] > pr[e1]) e1 = e;       // first max (tie: lower idx)
    int e2 = (e1 == 0) ? 1 : 0;
    for (int e = 0; e < 8; e++) if (e != e1 && e != e2 && pr[e] > pr[e2]) e2 = e;
    const float wsum = fmaxf(pr[e1] + pr[e2], 1e-6f);
    topk_id[2*t] = e1; topk_id[2*t+1] = e2;
    topk_w[2*t] = pr[e1] / wsum; topk_w[2*t+1] = pr[e2] / wsum;
  }
}

// ------- single-block: counts, bases, lb loss, deterministic slot assignment ----
__global__ __launch_bounds__(256) void k_stats(
    const int* __restrict__ topk_id, const float* __restrict__ topk_w,
    const float* __restrict__ probbuf,
    int* __restrict__ counts, int* __restrict__ bases,
    int* __restrict__ slots_of, int* __restrict__ tok_of,
    float* __restrict__ slot_w,
    float* __restrict__ lb_out)
{
  const int tid = threadIdx.x;
  __shared__ int s_scan[256][8];
  __shared__ int s_base[8];

  int ids[16];
  int lc[8] = {}, lc1[8] = {};
  float lsp[8] = {};
  #pragma unroll
  for (int j = 0; j < 8; j++){
    const int t = tid * 8 + j;
    const int e1 = topk_id[2*t], e2 = topk_id[2*t+1];
    ids[2*j] = e1; ids[2*j+1] = e2;
    lc[e1]++; lc[e2]++; lc1[e1]++;
    const float4 p0 = ((const float4*)(probbuf + t * 8))[0];
    const float4 p1 = ((const float4*)(probbuf + t * 8))[1];
    lsp[0] += p0.x; lsp[1] += p0.y; lsp[2] += p0.z; lsp[3] += p0.w;
    lsp[4] += p1.x; lsp[5] += p1.y; lsp[6] += p1.z; lsp[7] += p1.w;
  }
  #pragma unroll
  for (int e = 0; e < 8; e++) s_scan[tid][e] = lc[e];
  __syncthreads();
  for (int off = 1; off < 256; off <<= 1){
    int v[8];
    if (tid >= off){
      #pragma unroll
      for (int e = 0; e < 8; e++) v[e] = s_scan[tid - off][e];
    }
    __syncthreads();
    if (tid >= off){
      #pragma unroll
      for (int e = 0; e < 8; e++) s_scan[tid][e] += v[e];
    }
    __syncthreads();
  }
  int   rc1[8]; float rsp[8];
  #pragma unroll
  for (int e = 0; e < 8; e++){ rc1[e] = lc1[e]; rsp[e] = lsp[e]; }
  #pragma unroll
  for (int e = 0; e < 8; e++){
    #pragma unroll
    for (int o = 32; o > 0; o >>= 1){
      rc1[e] += __shfl_down(rc1[e], o);
      rsp[e] += __shfl_down(rsp[e], o);
    }
  }
  __shared__ int   s_c1[4][8];
  __shared__ float s_sp[4][8];
  if ((tid & 63) == 0){
    const int w = tid >> 6;
    #pragma unroll
    for (int e = 0; e < 8; e++){ s_c1[w][e] = rc1[e]; s_sp[w][e] = rsp[e]; }
  }
  __syncthreads();
  if (tid == 0){
    int b = 0; float lb = 0.f;
    for (int e = 0; e < 8; e++){
      const int tot = s_scan[255][e];
      counts[e] = tot; bases[e] = b; s_base[e] = b; b += tot;
      const int   c1 = s_c1[0][e] + s_c1[1][e] + s_c1[2][e] + s_c1[3][e];
      const float sp = s_sp[0][e] + s_sp[1][e] + s_sp[2][e] + s_sp[3][e];
      lb += (float)c1 * sp;
    }
    lb_out[0] = 8.f * lb * (1.f / ((float)T_TOK * (float)T_TOK));
  }
  __syncthreads();
  int rank[8];
  #pragma unroll
  for (int e = 0; e < 8; e++) rank[e] = s_scan[tid][e] - lc[e];   // exclusive prefix
  #pragma unroll
  for (int j = 0; j < 8; j++){
    const int t = tid * 8 + j;
    #pragma unroll
    for (int k = 0; k < 2; k++){
      const int e = ids[2*j + k];
      const int slot = s_base[e] + rank[e]++;
      slots_of[2*t + k] = slot;
      tok_of[slot] = t;
      slot_w[slot] = topk_w[2*t + k];
    }
  }
}

// -------- grouped GEMM, software-pipelined, A+B LDS double-buffered, 128x128 ------
// B staged straight from fp32 weights (load->cvt->ds_write issued one K-tile ahead,
// overlapped with MFMA). Compact grid: all blocks live, mt-loop absorbs imbalance.
// expert = blockIdx&7 (XCD-pinned). LDS chunk swizzle pos=(q+(row>>1))&3 keeps
// fragment ds_read_b128 conflict-free. Pad-row sources clamped (pure fn of d_in).
// MODE 0: grid 8e x (4ms x 16nt); C = silu(xn[tok_of[slot]] @ w1^T) -> bf16 Hg
// MODE 1: grid 8e x (4ms x 8nt x 2ks) split-K; C = partial(Hg @ w2^T) -> bf16 Og[ks]
template<int KD, int NDIM, int MODE>
__global__ __launch_bounds__(256) void k_gemm(
    const unsigned short* __restrict__ Ag,
    const float* __restrict__ Bw,
    const int* __restrict__ counts, const int* __restrict__ bases,
    const int* __restrict__ tok_of,
    unsigned short* __restrict__ Cout)
{
  const int e = blockIdx.x & 7;
  const int g = blockIdx.x >> 3;
  int nt, ms, kbase; size_t poff;
  if (MODE == 0){ nt = g & 15; ms = g >> 4; kbase = 0; poff = 0; }
  else { const int ks = g & 1; nt = (g >> 1) & 7; ms = g >> 4; kbase = ks * 1024;
         poff = (size_t)ks * SLOTPAD * NDIM; }
  const int M = counts[e];
  const int sbase = bases[e];

  __shared__ __align__(16) unsigned short As[2][128 * 32];
  __shared__ __align__(16) unsigned short Bs[2][128 * 32];

  const int tid = threadIdx.x;
  const int l = tid & 63;
  const int w = tid >> 6;
  const int wm = (w >> 1) * 64, wn = (w & 1) * 64;
  const int lrow = l & 15, lq = l >> 4;

  // staging chunk geometry: chunks c0=tid, c1=tid+256; c = row*4 + q
  const int row0 = tid >> 2, q0 = tid & 3;
  const int row1 = (tid + 256) >> 2, q1 = tid & 3;
  const int kc0 = ((q0 - (row0 >> 1)) & 3) * 8;
  const int kc1 = ((q1 - (row1 >> 1)) & 3) * 8;

  const float* Bb = Bw + (size_t)e * NDIM * KD + kbase;
  const float* brow0 = Bb + (size_t)(nt * 128 + row0) * KD + kc0;
  const float* brow1 = Bb + (size_t)(nt * 128 + row1) * KD + kc1;

  for (int mt = ms; mt * 128 < M; mt += 4){
    const unsigned short *arow0, *arow1;
    {
      const int v0 = min(mt * 128 + row0, M - 1);
      const int v1 = min(mt * 128 + row1, M - 1);
      const int r0 = (MODE == 0) ? tok_of[sbase + v0] : (sbase + v0);
      const int r1 = (MODE == 0) ? tok_of[sbase + v1] : (sbase + v1);
      arow0 = Ag + (size_t)r0 * KD + kbase + kc0;
      arow1 = Ag + (size_t)r1 * KD + kbase + kc1;
    }

    floatx4 acc[4][4] = {};

    // prologue: stage k-tile 0 into buffer 0
    GLDS(arow0, As[0] + tid * 8);
    GLDS(arow1, As[0] + (tid + 256) * 8);
    {
      const float4 a0 = ((const float4*)brow0)[0], a1 = ((const float4*)brow0)[1];
      const float4 b0 = ((const float4*)brow1)[0], b1 = ((const float4*)brow1)[1];
      ushort8 o;
      o[0]=f2bf(a0.x); o[1]=f2bf(a0.y); o[2]=f2bf(a0.z); o[3]=f2bf(a0.w);
      o[4]=f2bf(a1.x); o[5]=f2bf(a1.y); o[6]=f2bf(a1.z); o[7]=f2bf(a1.w);
      *(ushort8*)(Bs[0] + tid * 8) = o;
      ushort8 o2;
      o2[0]=f2bf(b0.x); o2[1]=f2bf(b0.y); o2[2]=f2bf(b0.z); o2[3]=f2bf(b0.w);
      o2[4]=f2bf(b1.x); o2[5]=f2bf(b1.y); o2[6]=f2bf(b1.z); o2[7]=f2bf(b1.w);
      *(ushort8*)(Bs[0] + (tid + 256) * 8) = o2;
    }

    for (int kk = 0; kk < 32; kk++){
      const int cur = kk & 1, nxt = cur ^ 1;
      __syncthreads();                         // buf[cur] ready; buf[nxt] free
      const bool more = (kk < 31);
      float4 a0, a1, b0, b1;
      if (more){
        const int ko = (kk + 1) * 32;
        GLDS(arow0 + ko, As[nxt] + tid * 8);
        GLDS(arow1 + ko, As[nxt] + (tid + 256) * 8);
        a0 = ((const float4*)(brow0 + ko))[0]; a1 = ((const float4*)(brow0 + ko))[1];
        b0 = ((const float4*)(brow1 + ko))[0]; b1 = ((const float4*)(brow1 + ko))[1];
      }
      bf16x8 af[4], bfv[4];
      #pragma unroll
      for (int mi = 0; mi < 4; mi++){
        const int row = wm + mi * 16 + lrow;
        const int p = (lq + (row >> 1)) & 3;
        af[mi] = *(const bf16x8*)(As[cur] + row * 32 + p * 8);
      }
      #pragma unroll
      for (int ni = 0; ni < 4; ni++){
        const int row = wn + ni * 16 + lrow;
        const int p = (lq + (row >> 1)) & 3;
        bfv[ni] = *(const bf16x8*)(Bs[cur] + row * 32 + p * 8);
      }
      #pragma unroll
      for (int mi = 0; mi < 4; mi++)
        #pragma unroll
        for (int ni = 0; ni < 4; ni++)
          acc[mi][ni] = __builtin_amdgcn_mfma_f32_16x16x32_bf16(af[mi], bfv[ni], acc[mi][ni], 0, 0, 0);
      if (more){
        ushort8 o;
        o[0]=f2bf(a0.x); o[1]=f2bf(a0.y); o[2]=f2bf(a0.z); o[3]=f2bf(a0.w);
        o[4]=f2bf(a1.x); o[5]=f2bf(a1.y); o[6]=f2bf(a1.z); o[7]=f2bf(a1.w);
        *(ushort8*)(Bs[nxt] + tid * 8) = o;
        ushort8 o2;
        o2[0]=f2bf(b0.x); o2[1]=f2bf(b0.y); o2[2]=f2bf(b0.z); o2[3]=f2bf(b0.w);
        o2[4]=f2bf(b1.x); o2[5]=f2bf(b1.y); o2[6]=f2bf(b1.z); o2[7]=f2bf(b1.w);
        *(ushort8*)(Bs[nxt] + (tid + 256) * 8) = o2;
      }
    }

    // epilogue: C/D layout col = lane&15, row = (lane>>4)*4 + r
    const int rb = lq * 4;
    #pragma unroll
    for (int mi = 0; mi < 4; mi++){
      #pragma unroll
      for (int r = 0; r < 4; r++){
        const int row = mt * 128 + wm + mi * 16 + rb + r;
        if (row < M){
          #pragma unroll
          for (int ni = 0; ni < 4; ni++){
            const int col = nt * 128 + wn + ni * 16 + (l & 15);
            const float v = acc[mi][ni][r];
            if (MODE == 0){
              const float s = v / (1.f + __expf(-v));   // silu
              Cout[(size_t)(sbase + row) * NDIM + col] = f2bf(s);
            } else {
              Cout[poff + (size_t)(sbase + row) * NDIM + col] = f2bf(v);
            }
          }
        }
      }
    }
    __syncthreads();   // protect As[0]/Bs[0] prologue of next mt-tile vs kk=31 readers
  }
}

// ------- residual combine: out = x + sc*(w0*(p0a+p0b) + w1*(p1a+p1b)) ----------
__global__ __launch_bounds__(256) void k_combine(
    const float* __restrict__ x, const unsigned short* __restrict__ Og,
    const int* __restrict__ slots_of, const float* __restrict__ slot_w,
    const float* __restrict__ scale,
    float* __restrict__ out)
{
  const int i = blockIdx.x * 256 + threadIdx.x;   // over T*D/8
  const int t = i >> 7;
  const int j = i & 127;
  const int s0 = slots_of[2*t], s1 = slots_of[2*t+1];
  const float w0 = slot_w[s0], w1 = slot_w[s1];
  const ushort8 a0 = ((const ushort8*)(Og + (size_t)s0 * DD))[j];
  const ushort8 a1 = ((const ushort8*)(Og + (size_t)SLOTPAD * DD + (size_t)s0 * DD))[j];
  const ushort8 b0 = ((const ushort8*)(Og + (size_t)s1 * DD))[j];
  const ushort8 b1 = ((const ushort8*)(Og + (size_t)SLOTPAD * DD + (size_t)s1 * DD))[j];
  const float4 x0 = ((const float4*)(x + (size_t)t * DD))[2*j];
  const float4 x1 = ((const float4*)(x + (size_t)t * DD))[2*j + 1];
  const float sc = 1.f / (1.f + __expf(-scale[0]));
  float o[8];
  #pragma unroll
  for (int q = 0; q < 8; q++)
    o[q] = sc * (w0 * (bf2f(a0[q]) + bf2f(a1[q])) + w1 * (bf2f(b0[q]) + bf2f(b1[q])));
  float4 o0, o1;
  o0.x = x0.x + o[0]; o0.y = x0.y + o[1]; o0.z = x0.z + o[2]; o0.w = x0.w + o[3];
  o1.x = x1.x + o[4]; o1.y = x1.y + o[5]; o1.z = x1.z + o[6]; o1.w = x1.w + o[7];
  ((float4*)(out + (size_t)t * DD))[2*j] = o0;
  ((float4*)(out + (size_t)t * DD))[2*j + 1] = o1;
}

extern "C" void kernel_launch(void* const* d_in, const int* in_sizes, int n_in,
                              void* d_out, int out_size, void* d_ws, size_t ws_size,
                              hipStream_t stream)
{
  const float* x     = (const float*)d_in[0];   // [2,1024,1024]
  const float* gw    = (const float*)d_in[1];   // [8,1024]
  const float* w1    = (const float*)d_in[2];   // [8,2048,1024]
  const float* w2    = (const float*)d_in[3];   // [8,1024,2048]
  const float* nw    = (const float*)d_in[4];   // [1024]
  const float* scale = (const float*)d_in[5];   // [1]
  float* out = (float*)d_out;                   // 2097152 + 1 (lb loss)

  char* ws = (char*)d_ws;
  int*   counts  = (int*)(ws + 0);
  int*   bases   = (int*)(ws + 64);
  int*   topk_id = (int*)(ws + 1024);            // 16 KB
  float* topk_w  = (float*)(ws + 20480);         // 16 KB
  int*   slots_of= (int*)(ws + 40960);           // 16 KB
  float* slot_w  = (float*)(ws + 61440);         // 16.5 KB
  int*   tok_of  = (int*)(ws + 81920);           // 16 KB
  float* probbuf = (float*)(ws + 102400);        // 64 KB
  unsigned short* xn  = (unsigned short*)(ws + 262144);            // 4 MB
  unsigned short* Hg  = xn + (size_t)T_TOK * DD;                   // 17.3 MB
  unsigned short* Og  = Hg + (size_t)SLOTPAD * FF;                 // 2x 8.65 MB partials

  k_rms_router<<<T_TOK, 256, 0, stream>>>(x, gw, nw, xn, topk_id, topk_w, probbuf);
  k_stats<<<1, 256, 0, stream>>>(topk_id, topk_w, probbuf, counts, bases,
                                 slots_of, tok_of, slot_w, out + (size_t)T_TOK * DD);
  k_gemm<1024, 2048, 0><<<EE * 4 * 16, 256, 0, stream>>>(xn, w1, counts, bases, tok_of, Hg);
  k_gemm<2048, 1024, 1><<<EE * 4 * 8 * 2, 256, 0, stream>>>(Hg, w2, counts, bases, nullptr, Og);
  k_combine<<<T_TOK * DD / 8 / 256, 256, 0, stream>>>(x, Og, slots_of, slot_w, scale, out);
}

// Round 8
// 268.060 us; speedup vs baseline: 1.3163x; 1.0926x over previous
//
#include <hip/hip_runtime.h>
#include <stdint.h>

#define T_TOK 2048
#define DD 1024
#define EE 8
#define FF 2048
#define NSLOT 4096     // T*K
#define SLOTPAD 4224   // NSLOT + 128 pad rows

typedef __attribute__((ext_vector_type(8))) __bf16 bf16x8;
typedef __attribute__((ext_vector_type(4))) float floatx4;
typedef __attribute__((ext_vector_type(8))) unsigned short ushort8;

__device__ __forceinline__ unsigned short f2bf(float f){
  union { float f; unsigned u; } v; v.f = f;
  unsigned r = v.u + 0x7fffu + ((v.u >> 16) & 1u);
  return (unsigned short)(r >> 16);
}
__device__ __forceinline__ float bf2f(unsigned short h){
  union { unsigned u; float f; } v; v.u = (unsigned)h << 16; return v.f;
}

#define GLDS(src, dst) __builtin_amdgcn_global_load_lds( \
    (__attribute__((address_space(1))) unsigned int*)(src), \
    (__attribute__((address_space(3))) unsigned int*)(dst), 16, 0, 0)

// ---------------- RMSNorm + router (one block per token, NO global atomics) ----
__global__ __launch_bounds__(256) void k_rms_router(
    const float* __restrict__ x, const float* __restrict__ gw,
    const float* __restrict__ nw,
    unsigned short* __restrict__ xn,
    int* __restrict__ topk_id, float* __restrict__ topk_w,
    float* __restrict__ probbuf)
{
  const int t = blockIdx.x, tid = threadIdx.x;
  const float4 xv = ((const float4*)(x + (size_t)t * DD))[tid];
  float ss = xv.x*xv.x + xv.y*xv.y + xv.z*xv.z + xv.w*xv.w;
  #pragma unroll
  for (int o = 32; o > 0; o >>= 1) ss += __shfl_down(ss, o);
  __shared__ float s_ss[4];
  __shared__ float s_p[4][8];
  if ((tid & 63) == 0) s_ss[tid >> 6] = ss;
  __syncthreads();
  const float tot = s_ss[0] + s_ss[1] + s_ss[2] + s_ss[3];
  const float inv = rsqrtf(tot * (1.0f / DD) + 1.1920929e-7f);
  const float4 nv = ((const float4*)nw)[tid];
  float4 xnv;
  xnv.x = xv.x*inv*nv.x; xnv.y = xv.y*inv*nv.y;
  xnv.z = xv.z*inv*nv.z; xnv.w = xv.w*inv*nv.w;
  ushort4 bv; bv.x = f2bf(xnv.x); bv.y = f2bf(xnv.y); bv.z = f2bf(xnv.z); bv.w = f2bf(xnv.w);
  ((ushort4*)(xn + (size_t)t * DD))[tid] = bv;
  float p[8];
  #pragma unroll
  for (int e = 0; e < 8; e++){
    const float4 g = ((const float4*)(gw + e * DD))[tid];
    p[e] = xnv.x*g.x + xnv.y*g.y + xnv.z*g.z + xnv.w*g.w;
  }
  #pragma unroll
  for (int e = 0; e < 8; e++){
    #pragma unroll
    for (int o = 32; o > 0; o >>= 1) p[e] += __shfl_down(p[e], o);
  }
  if ((tid & 63) == 0){
    #pragma unroll
    for (int e = 0; e < 8; e++) s_p[tid >> 6][e] = p[e];
  }
  __syncthreads();
  if (tid == 0){
    float lg[8], pr[8];
    #pragma unroll
    for (int e = 0; e < 8; e++) lg[e] = s_p[0][e] + s_p[1][e] + s_p[2][e] + s_p[3][e];
    float mx = lg[0];
    for (int e = 1; e < 8; e++) mx = fmaxf(mx, lg[e]);
    float sum = 0.f;
    for (int e = 0; e < 8; e++){ pr[e] = __expf(lg[e] - mx); sum += pr[e]; }
    const float is = 1.f / sum;
    for (int e = 0; e < 8; e++) pr[e] *= is;
    #pragma unroll
    for (int e = 0; e < 8; e++) probbuf[t * 8 + e] = pr[e];
    int e1 = 0;
    for (int e = 1; e < 8; e++) if (pr[e] > pr[e1]) e1 = e;       // first max (tie: lower idx)
    int e2 = (e1 == 0) ? 1 : 0;
    for (int e = 0; e < 8; e++) if (e != e1 && e != e2 && pr[e] > pr[e2]) e2 = e;
    const float wsum = fmaxf(pr[e1] + pr[e2], 1e-6f);
    topk_id[2*t] = e1; topk_id[2*t+1] = e2;
    topk_w[2*t] = pr[e1] / wsum; topk_w[2*t+1] = pr[e2] / wsum;
  }
}

// ------- single-block: counts, bases, lb loss, deterministic slot assignment ----
__global__ __launch_bounds__(256) void k_stats(
    const int* __restrict__ topk_id, const float* __restrict__ topk_w,
    const float* __restrict__ probbuf,
    int* __restrict__ counts, int* __restrict__ bases,
    int* __restrict__ slots_of, int* __restrict__ tok_of,
    float* __restrict__ slot_w,
    float* __restrict__ lb_out)
{
  const int tid = threadIdx.x;
  __shared__ int s_scan[256][8];
  __shared__ int s_base[8];

  int ids[16];
  int lc[8] = {}, lc1[8] = {};
  float lsp[8] = {};
  #pragma unroll
  for (int j = 0; j < 8; j++){
    const int t = tid * 8 + j;
    const int e1 = topk_id[2*t], e2 = topk_id[2*t+1];
    ids[2*j] = e1; ids[2*j+1] = e2;
    lc[e1]++; lc[e2]++; lc1[e1]++;
    const float4 p0 = ((const float4*)(probbuf + t * 8))[0];
    const float4 p1 = ((const float4*)(probbuf + t * 8))[1];
    lsp[0] += p0.x; lsp[1] += p0.y; lsp[2] += p0.z; lsp[3] += p0.w;
    lsp[4] += p1.x; lsp[5] += p1.y; lsp[6] += p1.z; lsp[7] += p1.w;
  }
  #pragma unroll
  for (int e = 0; e < 8; e++) s_scan[tid][e] = lc[e];
  __syncthreads();
  for (int off = 1; off < 256; off <<= 1){
    int v[8];
    if (tid >= off){
      #pragma unroll
      for (int e = 0; e < 8; e++) v[e] = s_scan[tid - off][e];
    }
    __syncthreads();
    if (tid >= off){
      #pragma unroll
      for (int e = 0; e < 8; e++) s_scan[tid][e] += v[e];
    }
    __syncthreads();
  }
  int   rc1[8]; float rsp[8];
  #pragma unroll
  for (int e = 0; e < 8; e++){ rc1[e] = lc1[e]; rsp[e] = lsp[e]; }
  #pragma unroll
  for (int e = 0; e < 8; e++){
    #pragma unroll
    for (int o = 32; o > 0; o >>= 1){
      rc1[e] += __shfl_down(rc1[e], o);
      rsp[e] += __shfl_down(rsp[e], o);
    }
  }
  __shared__ int   s_c1[4][8];
  __shared__ float s_sp[4][8];
  if ((tid & 63) == 0){
    const int w = tid >> 6;
    #pragma unroll
    for (int e = 0; e < 8; e++){ s_c1[w][e] = rc1[e]; s_sp[w][e] = rsp[e]; }
  }
  __syncthreads();
  if (tid == 0){
    int b = 0; float lb = 0.f;
    for (int e = 0; e < 8; e++){
      const int tot = s_scan[255][e];
      counts[e] = tot; bases[e] = b; s_base[e] = b; b += tot;
      const int   c1 = s_c1[0][e] + s_c1[1][e] + s_c1[2][e] + s_c1[3][e];
      const float sp = s_sp[0][e] + s_sp[1][e] + s_sp[2][e] + s_sp[3][e];
      lb += (float)c1 * sp;
    }
    lb_out[0] = 8.f * lb * (1.f / ((float)T_TOK * (float)T_TOK));
  }
  __syncthreads();
  int rank[8];
  #pragma unroll
  for (int e = 0; e < 8; e++) rank[e] = s_scan[tid][e] - lc[e];   // exclusive prefix
  #pragma unroll
  for (int j = 0; j < 8; j++){
    const int t = tid * 8 + j;
    #pragma unroll
    for (int k = 0; k < 2; k++){
      const int e = ids[2*j + k];
      const int slot = s_base[e] + rank[e]++;
      slots_of[2*t + k] = slot;
      tok_of[slot] = t;
      slot_w[slot] = topk_w[2*t + k];
    }
  }
}

// -------- grouped GEMM, 128x64 tile, dbuf pipeline, 4 blocks/CU --------------------
// Tile halved vs r7 to double live blocks (1024 = 4/CU = 16 waves/CU) so inter-block
// MFMA overlap hides the staging latency. Each wave: 64x32 (acc[4][2]).
// B staged straight from fp32 weights (load->cvt->ds_write one K-tile ahead).
// expert = blockIdx&7 (XCD-pinned). LDS chunk swizzle pos=(q+(row>>1))&3 keeps
// fragment ds_read_b128 conflict-free. Pad-row sources clamped (pure fn of d_in).
// MODE 0: grid 8e x (4ms x 32nt); C = silu(xn[tok_of[slot]] @ w1^T) -> bf16 Hg
// MODE 1: grid 8e x (4ms x 16nt x 2ks) split-K; C = partial(Hg @ w2^T) -> bf16 Og[ks]
template<int KD, int NDIM, int MODE>
__global__ __launch_bounds__(256) void k_gemm(
    const unsigned short* __restrict__ Ag,
    const float* __restrict__ Bw,
    const int* __restrict__ counts, const int* __restrict__ bases,
    const int* __restrict__ tok_of,
    unsigned short* __restrict__ Cout)
{
  const int e = blockIdx.x & 7;
  const int g = blockIdx.x >> 3;
  int nt, ms, kbase; size_t poff;
  if (MODE == 0){ nt = g & 31; ms = g >> 5; kbase = 0; poff = 0; }
  else { const int ks = g & 1; nt = (g >> 1) & 15; ms = g >> 5; kbase = ks * 1024;
         poff = (size_t)ks * SLOTPAD * NDIM; }
  const int M = counts[e];
  if (M == 0) return;
  const int sbase = bases[e];

  __shared__ __align__(16) unsigned short As[2][128 * 32];
  __shared__ __align__(16) unsigned short Bs[2][64 * 32];

  const int tid = threadIdx.x;
  const int l = tid & 63;
  const int w = tid >> 6;
  const int wm = (w >> 1) * 64, wn = (w & 1) * 32;
  const int lrow = l & 15, lq = l >> 4;

  // A staging: 512 chunks of 16B, 2/thread; B staging: 256 chunks, 1/thread
  const int ar0 = tid >> 2, ar1 = (tid + 256) >> 2, aq = tid & 3;
  const int akc0 = ((aq - (ar0 >> 1)) & 3) * 8;
  const int akc1 = ((aq - (ar1 >> 1)) & 3) * 8;
  const int br = tid >> 2, bq = tid & 3;
  const int bkc = ((bq - (br >> 1)) & 3) * 8;

  const float* brow = Bw + (size_t)e * NDIM * KD + (size_t)(nt * 64 + br) * KD + kbase + bkc;

  for (int mt = ms; mt * 128 < M; mt += 4){
    const unsigned short *arow0, *arow1;
    {
      const int v0 = min(mt * 128 + ar0, M - 1);
      const int v1 = min(mt * 128 + ar1, M - 1);
      const int r0 = (MODE == 0) ? tok_of[sbase + v0] : (sbase + v0);
      const int r1 = (MODE == 0) ? tok_of[sbase + v1] : (sbase + v1);
      arow0 = Ag + (size_t)r0 * KD + kbase + akc0;
      arow1 = Ag + (size_t)r1 * KD + kbase + akc1;
    }

    floatx4 acc[4][2] = {};

    // prologue: stage k-tile 0 into buffer 0
    GLDS(arow0, As[0] + tid * 8);
    GLDS(arow1, As[0] + (tid + 256) * 8);
    {
      const float4 b0 = ((const float4*)brow)[0], b1 = ((const float4*)brow)[1];
      ushort8 o;
      o[0]=f2bf(b0.x); o[1]=f2bf(b0.y); o[2]=f2bf(b0.z); o[3]=f2bf(b0.w);
      o[4]=f2bf(b1.x); o[5]=f2bf(b1.y); o[6]=f2bf(b1.z); o[7]=f2bf(b1.w);
      *(ushort8*)(Bs[0] + tid * 8) = o;
    }

    for (int kk = 0; kk < 32; kk++){
      const int cur = kk & 1, nxt = cur ^ 1;
      __syncthreads();                         // buf[cur] ready; buf[nxt] free
      const bool more = (kk < 31);
      float4 b0, b1;
      if (more){
        const int ko = (kk + 1) * 32;
        GLDS(arow0 + ko, As[nxt] + tid * 8);
        GLDS(arow1 + ko, As[nxt] + (tid + 256) * 8);
        b0 = ((const float4*)(brow + ko))[0];
        b1 = ((const float4*)(brow + ko))[1];
      }
      bf16x8 af[4], bfv[2];
      #pragma unroll
      for (int mi = 0; mi < 4; mi++){
        const int row = wm + mi * 16 + lrow;
        const int p = (lq + (row >> 1)) & 3;
        af[mi] = *(const bf16x8*)(As[cur] + row * 32 + p * 8);
      }
      #pragma unroll
      for (int ni = 0; ni < 2; ni++){
        const int row = wn + ni * 16 + lrow;
        const int p = (lq + (row >> 1)) & 3;
        bfv[ni] = *(const bf16x8*)(Bs[cur] + row * 32 + p * 8);
      }
      #pragma unroll
      for (int mi = 0; mi < 4; mi++)
        #pragma unroll
        for (int ni = 0; ni < 2; ni++)
          acc[mi][ni] = __builtin_amdgcn_mfma_f32_16x16x32_bf16(af[mi], bfv[ni], acc[mi][ni], 0, 0, 0);
      if (more){
        ushort8 o;
        o[0]=f2bf(b0.x); o[1]=f2bf(b0.y); o[2]=f2bf(b0.z); o[3]=f2bf(b0.w);
        o[4]=f2bf(b1.x); o[5]=f2bf(b1.y); o[6]=f2bf(b1.z); o[7]=f2bf(b1.w);
        *(ushort8*)(Bs[nxt] + tid * 8) = o;
      }
    }

    // epilogue: C/D layout col = lane&15, row = (lane>>4)*4 + r
    const int rb = lq * 4;
    #pragma unroll
    for (int mi = 0; mi < 4; mi++){
      #pragma unroll
      for (int r = 0; r < 4; r++){
        const int row = mt * 128 + wm + mi * 16 + rb + r;
        if (row < M){
          #pragma unroll
          for (int ni = 0; ni < 2; ni++){
            const int col = nt * 64 + wn + ni * 16 + (l & 15);
            const float v = acc[mi][ni][r];
            if (MODE == 0){
              const float s = v / (1.f + __expf(-v));   // silu
              Cout[(size_t)(sbase + row) * NDIM + col] = f2bf(s);
            } else {
              Cout[poff + (size_t)(sbase + row) * NDIM + col] = f2bf(v);
            }
          }
        }
      }
    }
    __syncthreads();   // protect buffer reuse across mt-tiles
  }
}

// ------- residual combine: out = x + sc*(w0*(p0a+p0b) + w1*(p1a+p1b)) ----------
__global__ __launch_bounds__(256) void k_combine(
    const float* __restrict__ x, const unsigned short* __restrict__ Og,
    const int* __restrict__ slots_of, const float* __restrict__ slot_w,
    const float* __restrict__ scale,
    float* __restrict__ out)
{
  const int i = blockIdx.x * 256 + threadIdx.x;   // over T*D/8
  const int t = i >> 7;
  const int j = i & 127;
  const int s0 = slots_of[2*t], s1 = slots_of[2*t+1];
  const float w0 = slot_w[s0], w1 = slot_w[s1];
  const ushort8 a0 = ((const ushort8*)(Og + (size_t)s0 * DD))[j];
  const ushort8 a1 = ((const ushort8*)(Og + (size_t)SLOTPAD * DD + (size_t)s0 * DD))[j];
  const ushort8 b0 = ((const ushort8*)(Og + (size_t)s1 * DD))[j];
  const ushort8 b1 = ((const ushort8*)(Og + (size_t)SLOTPAD * DD + (size_t)s1 * DD))[j];
  const float4 x0 = ((const float4*)(x + (size_t)t * DD))[2*j];
  const float4 x1 = ((const float4*)(x + (size_t)t * DD))[2*j + 1];
  const float sc = 1.f / (1.f + __expf(-scale[0]));
  float o[8];
  #pragma unroll
  for (int q = 0; q < 8; q++)
    o[q] = sc * (w0 * (bf2f(a0[q]) + bf2f(a1[q])) + w1 * (bf2f(b0[q]) + bf2f(b1[q])));
  float4 o0, o1;
  o0.x = x0.x + o[0]; o0.y = x0.y + o[1]; o0.z = x0.z + o[2]; o0.w = x0.w + o[3];
  o1.x = x1.x + o[4]; o1.y = x1.y + o[5]; o1.z = x1.z + o[6]; o1.w = x1.w + o[7];
  ((float4*)(out + (size_t)t * DD))[2*j] = o0;
  ((float4*)(out + (size_t)t * DD))[2*j + 1] = o1;
}

extern "C" void kernel_launch(void* const* d_in, const int* in_sizes, int n_in,
                              void* d_out, int out_size, void* d_ws, size_t ws_size,
                              hipStream_t stream)
{
  const float* x     = (const float*)d_in[0];   // [2,1024,1024]
  const float* gw    = (const float*)d_in[1];   // [8,1024]
  const float* w1    = (const float*)d_in[2];   // [8,2048,1024]
  const float* w2    = (const float*)d_in[3];   // [8,1024,2048]
  const float* nw    = (const float*)d_in[4];   // [1024]
  const float* scale = (const float*)d_in[5];   // [1]
  float* out = (float*)d_out;                   // 2097152 + 1 (lb loss)

  char* ws = (char*)d_ws;
  int*   counts  = (int*)(ws + 0);
  int*   bases   = (int*)(ws + 64);
  int*   topk_id = (int*)(ws + 1024);            // 16 KB
  float* topk_w  = (float*)(ws + 20480);         // 16 KB
  int*   slots_of= (int*)(ws + 40960);           // 16 KB
  float* slot_w  = (float*)(ws + 61440);         // 16.5 KB
  int*   tok_of  = (int*)(ws + 81920);           // 16 KB
  float* probbuf = (float*)(ws + 102400);        // 64 KB
  unsigned short* xn  = (unsigned short*)(ws + 262144);            // 4 MB
  unsigned short* Hg  = xn + (size_t)T_TOK * DD;                   // 17.3 MB
  unsigned short* Og  = Hg + (size_t)SLOTPAD * FF;                 // 2x 8.65 MB partials

  k_rms_router<<<T_TOK, 256, 0, stream>>>(x, gw, nw, xn, topk_id, topk_w, probbuf);
  k_stats<<<1, 256, 0, stream>>>(topk_id, topk_w, probbuf, counts, bases,
                                 slots_of, tok_of, slot_w, out + (size_t)T_TOK * DD);
  k_gemm<1024, 2048, 0><<<EE * 4 * 32, 256, 0, stream>>>(xn, w1, counts, bases, tok_of, Hg);
  k_gemm<2048, 1024, 1><<<EE * 4 * 16 * 2, 256, 0, stream>>>(Hg, w2, counts, bases, nullptr, Og);
  k_combine<<<T_TOK * DD / 8 / 256, 256, 0, stream>>>(x, Og, slots_of, slot_w, scale, out);
}